// Round 1
// baseline (203.673 us; speedup 1.0000x reference)
//
#include <hip/hip_runtime.h>

// EmbeddingShard: out[n, :] = (W_full[tok[n], :] + sum_s b[s, :]) / SHARDS
// tok: [32768] int32, W: [8, 6300, 4096] f32 (contiguous == W_full [50400,4096]),
// b: [8, 4096] f32, out: [32768, 4096] f32.
// Pure memory-bound gather: ~512 MiB gather-read + 512 MiB write.

#define OUT_DIM 4096
#define SHARDS 8

// Step 1: bsum[j] = (sum_s b[s][j]) * 0.125  (pre-scaled by 1/SHARDS)
__global__ void bias_sum_kernel(const float* __restrict__ b, float* __restrict__ bsum) {
    int i = blockIdx.x * blockDim.x + threadIdx.x;
    if (i < OUT_DIM) {
        float s = 0.0f;
#pragma unroll
        for (int sh = 0; sh < SHARDS; ++sh) s += b[sh * OUT_DIM + i];
        bsum[i] = s * 0.125f;
    }
}

// Step 2: gather + fused bias/scale. 256 threads/block; thread t owns columns
// {c*1024 + t*4 .. +3 | c in 0..3}; bias for those 16 columns preloaded into
// registers once per block, then grid-stride over token rows.
__global__ __launch_bounds__(256) void embed_gather_kernel(
        const int* __restrict__ tok, const float* __restrict__ W,
        const float* __restrict__ bsum, float* __restrict__ out, int n) {
    const int t = threadIdx.x;  // 0..255
    const float4* bsum4 = reinterpret_cast<const float4*>(bsum);

    float4 bias[4];
#pragma unroll
    for (int c = 0; c < 4; ++c) bias[c] = bsum4[c * 256 + t];

    for (int row = blockIdx.x; row < n; row += gridDim.x) {
        const long long id = tok[row];  // wave-uniform broadcast load
        const float4* __restrict__ wrow =
            reinterpret_cast<const float4*>(W + id * (long long)OUT_DIM);
        float4* __restrict__ orow =
            reinterpret_cast<float4*>(out + (long long)row * OUT_DIM);
#pragma unroll
        for (int c = 0; c < 4; ++c) {
            float4 w = wrow[c * 256 + t];
            float4 r;
            r.x = fmaf(w.x, 0.125f, bias[c].x);
            r.y = fmaf(w.y, 0.125f, bias[c].y);
            r.z = fmaf(w.z, 0.125f, bias[c].z);
            r.w = fmaf(w.w, 0.125f, bias[c].w);
            orow[c * 256 + t] = r;
        }
    }
}

extern "C" void kernel_launch(void* const* d_in, const int* in_sizes, int n_in,
                              void* d_out, int out_size, void* d_ws, size_t ws_size,
                              hipStream_t stream) {
    const int*   tok = (const int*)d_in[0];
    const float* W   = (const float*)d_in[1];
    const float* b   = (const float*)d_in[2];
    float*       out = (float*)d_out;
    float*       bsum = (float*)d_ws;  // 4096 floats = 16 KB scratch

    const int n = in_sizes[0];  // 32768 tokens

    bias_sum_kernel<<<(OUT_DIM + 255) / 256, 256, 0, stream>>>(b, bsum);

    // 2048 blocks = 8 blocks/CU on 256 CUs; grid-stride over rows.
    int grid = n < 2048 ? n : 2048;
    embed_gather_kernel<<<grid, 256, 0, stream>>>(tok, W, bsum, out, n);
}

// Round 2
// 170.083 us; speedup vs baseline: 1.1975x; 1.1975x over previous
//
#include <hip/hip_runtime.h>

// EmbeddingShard: out[n, :] = (W_full[tok[n], :] + sum_s b[s, :]) / SHARDS
// tok: [32768] int32, W: [8, 6300, 4096] f32 (contiguous == W_full [50400,4096]),
// b: [8, 4096] f32, out: [32768, 4096] f32.
// Memory-bound gather: ~512 MiB streamed write + ~390-512 MiB gather read.
// R2: non-temporal output stores (preserve W lines in L2/L3) + 2 rows/iter MLP.

#define OUT_DIM 4096
#define SHARDS 8

typedef float f32x4 __attribute__((ext_vector_type(4)));

// Step 1: bsum[j] = (sum_s b[s][j]) * 0.125  (pre-scaled by 1/SHARDS)
__global__ void bias_sum_kernel(const float* __restrict__ b, float* __restrict__ bsum) {
    int i = blockIdx.x * blockDim.x + threadIdx.x;
    if (i < OUT_DIM) {
        float s = 0.0f;
#pragma unroll
        for (int sh = 0; sh < SHARDS; ++sh) s += b[sh * OUT_DIM + i];
        bsum[i] = s * 0.125f;
    }
}

// Step 2: gather + fused bias/scale. 256 threads/block; thread t owns columns
// {c*1024 + t*4 .. +3 | c in 0..3}. Two rows per iteration for 8 outstanding
// 16B loads; output written with non-temporal stores so the streamed-once
// output doesn't evict W-table lines from L2/L3.
__global__ __launch_bounds__(256) void embed_gather_kernel(
        const int* __restrict__ tok, const float* __restrict__ W,
        const float* __restrict__ bsum, float* __restrict__ out, int n) {
    const int t = threadIdx.x;  // 0..255
    const f32x4* bsum4 = reinterpret_cast<const f32x4*>(bsum);

    f32x4 bias[4];
#pragma unroll
    for (int c = 0; c < 4; ++c) bias[c] = bsum4[c * 256 + t];

    for (int row = blockIdx.x * 2; row < n; row += gridDim.x * 2) {
        const int row1 = row + 1;
        const bool has1 = (row1 < n);
        const long long id0 = tok[row];
        const long long id1 = has1 ? tok[row1] : id0;
        const f32x4* __restrict__ w0 =
            reinterpret_cast<const f32x4*>(W + id0 * (long long)OUT_DIM);
        const f32x4* __restrict__ w1 =
            reinterpret_cast<const f32x4*>(W + id1 * (long long)OUT_DIM);

        f32x4 a[4], c4[4];
#pragma unroll
        for (int c = 0; c < 4; ++c) a[c] = w0[c * 256 + t];
#pragma unroll
        for (int c = 0; c < 4; ++c) c4[c] = w1[c * 256 + t];

        f32x4* o0 = reinterpret_cast<f32x4*>(out + (long long)row * OUT_DIM);
        f32x4* o1 = reinterpret_cast<f32x4*>(out + (long long)row1 * OUT_DIM);
#pragma unroll
        for (int c = 0; c < 4; ++c) {
            f32x4 r = a[c] * 0.125f + bias[c];
            __builtin_nontemporal_store(r, &o0[c * 256 + t]);
        }
        if (has1) {
#pragma unroll
            for (int c = 0; c < 4; ++c) {
                f32x4 r = c4[c] * 0.125f + bias[c];
                __builtin_nontemporal_store(r, &o1[c * 256 + t]);
            }
        }
    }
}

extern "C" void kernel_launch(void* const* d_in, const int* in_sizes, int n_in,
                              void* d_out, int out_size, void* d_ws, size_t ws_size,
                              hipStream_t stream) {
    const int*   tok = (const int*)d_in[0];
    const float* W   = (const float*)d_in[1];
    const float* b   = (const float*)d_in[2];
    float*       out = (float*)d_out;
    float*       bsum = (float*)d_ws;  // 4096 floats = 16 KB scratch

    const int n = in_sizes[0];  // 32768 tokens

    bias_sum_kernel<<<(OUT_DIM + 255) / 256, 256, 0, stream>>>(b, bsum);

    // 2048 blocks, 2 rows per block-iteration; grid-stride over rows.
    int pairs = (n + 1) / 2;
    int grid = pairs < 2048 ? pairs : 2048;
    embed_gather_kernel<<<grid, 256, 0, stream>>>(tok, W, bsum, out, n);
}